// Round 1
// baseline (821.511 us; speedup 1.0000x reference)
//
#include <hip/hip_runtime.h>
#include <math.h>

#define N_NODES 10000
#define D_MODEL 128
#define K_STATE 16
#define S_LEN 5
#define E_EDGES 320000
#define P_EDGES 80000   // E/(S-1)
#define LN_EPS 1e-5f

// ---------------------------------------------------------------------------
// Kernel 1: tokenize scatter.
// One edge-step per 32 threads; each thread handles 4 contiguous floats.
// seg layout: [N, 4, D] (token s+1 for node n at seg[(n*4+s)*D]).
// deg layout: [N, 4].
// ---------------------------------------------------------------------------
__global__ __launch_bounds__(256) void tokenize_scatter(
    const float* __restrict__ x,
    const int* __restrict__ edge_index,
    const int* __restrict__ edge_type,
    const int* __restrict__ perms,
    const float* __restrict__ rel_table,
    float* __restrict__ seg,
    float* __restrict__ deg)
{
    int gid = blockIdx.x * blockDim.x + threadIdx.x;
    int es = gid >> 5;          // edge-step id in [0, 4*P)
    int lane = gid & 31;        // 0..31 -> 4 floats each
    if (es >= 4 * P_EDGES) return;
    int s = es / P_EDGES;
    int p = es - s * P_EDGES;
    int e   = perms[s * P_EDGES + p];
    int src = edge_index[e];
    int dst = edge_index[E_EDGES + e];
    int et  = edge_type[e];

    const float4* xs = (const float4*)(x + (size_t)src * D_MODEL);
    const float4* rs = (const float4*)(rel_table + (size_t)et * D_MODEL);
    float4 xv = xs[lane];
    float4 rv = rs[lane];

    float* outp = seg + ((size_t)dst * 4 + s) * D_MODEL + lane * 4;
    atomicAdd(outp + 0, xv.x + rv.x);
    atomicAdd(outp + 1, xv.y + rv.y);
    atomicAdd(outp + 2, xv.z + rv.z);
    atomicAdd(outp + 3, xv.w + rv.w);
    if (lane == 0) atomicAdd(deg + (size_t)dst * 4 + s, 1.0f);
}

// ---------------------------------------------------------------------------
// Kernel 2: per-node compute. Block = 128 threads = one node; tid = dim.
// ---------------------------------------------------------------------------
__global__ __launch_bounds__(128) void node_update(
    const float* __restrict__ x,
    const float* __restrict__ seg,
    const float* __restrict__ deg,
    const float* __restrict__ log_A,
    const float* __restrict__ W_B,
    const float* __restrict__ W_C,
    const float* __restrict__ W_delta,
    const float* __restrict__ b_delta,
    const float* __restrict__ W_g,
    const float* __restrict__ b_g,
    const float* __restrict__ W_out,
    const float* __restrict__ b_out,
    const float* __restrict__ ln_g,
    const float* __restrict__ ln_b,
    float* __restrict__ out)
{
    const int n = blockIdx.x;
    const int tid = threadIdx.x;      // 0..127
    const int TS = 132;               // padded LDS stride (bank-conflict free)

    __shared__ float tok[5 * 132];
    __shared__ float dlt[5 * 132];
    __shared__ float Bc[5 * 16];
    __shared__ float Cc[5 * 16];
    __shared__ float so[128];
    __shared__ float red[128];
    __shared__ float red2[128];

    // ---- build tokens: s=0 is x, s=1..4 are normalized segment sums ----
    float xv = x[(size_t)n * D_MODEL + tid];
    tok[0 * TS + tid] = xv;
    #pragma unroll
    for (int s = 1; s < 5; ++s) {
        float dv = deg[(size_t)n * 4 + (s - 1)];
        float inv = 1.0f / fmaxf(dv, 1.0f);
        tok[s * TS + tid] = seg[((size_t)n * 4 + (s - 1)) * D_MODEL + tid] * inv;
    }
    __syncthreads();

    // ---- deltas = softplus(tokens @ W_delta + b_delta) ----
    float z[5];
    {
        float bd = b_delta[tid];
        #pragma unroll
        for (int s = 0; s < 5; ++s) z[s] = bd;
        for (int d = 0; d < 128; ++d) {
            float w = W_delta[d * 128 + tid];
            #pragma unroll
            for (int s = 0; s < 5; ++s) z[s] = fmaf(tok[s * TS + d], w, z[s]);
        }
        #pragma unroll
        for (int s = 0; s < 5; ++s) {
            float zz = z[s];
            dlt[s * TS + tid] = (zz > 15.0f) ? zz : log1pf(__expf(zz));
        }
    }

    // ---- B = tokens @ W_B, C = tokens @ W_C (160 small dot products) ----
    for (int idx = tid; idx < 160; idx += 128) {
        int m = idx >= 80;
        int r = idx - m * 80;
        int s = r >> 4;
        int k = r & 15;
        const float* W = m ? W_C : W_B;
        float acc = 0.0f;
        for (int d = 0; d < 128; ++d)
            acc = fmaf(tok[s * TS + d], W[d * K_STATE + k], acc);
        if (m) Cc[s * 16 + k] = acc; else Bc[s * 16 + k] = acc;
    }
    __syncthreads();

    // ---- selective scan, forward + backward (recompute A,Bx per step) ----
    float Ac[16];
    #pragma unroll
    for (int k = 0; k < 16; ++k) Ac[k] = -__expf(log_A[tid * 16 + k]);
    float tv[5], dl[5];
    #pragma unroll
    for (int s = 0; s < 5; ++s) {
        tv[s] = tok[s * TS + tid];
        dl[s] = dlt[s * TS + tid];
    }

    float total = 0.0f;
    {   // forward
        float st[16];
        #pragma unroll
        for (int k = 0; k < 16; ++k) st[k] = 0.0f;
        #pragma unroll
        for (int s = 0; s < 5; ++s) {
            float dtv = dl[s] * tv[s];
            float y = 0.0f;
            #pragma unroll
            for (int k = 0; k < 16; ++k) {
                float A = __expf(dl[s] * Ac[k]);
                st[k] = fmaf(A, st[k], dtv * Bc[s * 16 + k]);
                y = fmaf(st[k], Cc[s * 16 + k], y);
            }
            total += y;
        }
    }
    {   // backward (reversed token order; per-token quantities identical)
        float st[16];
        #pragma unroll
        for (int k = 0; k < 16; ++k) st[k] = 0.0f;
        #pragma unroll
        for (int s = 4; s >= 0; --s) {
            float dtv = dl[s] * tv[s];
            float y = 0.0f;
            #pragma unroll
            for (int k = 0; k < 16; ++k) {
                float A = __expf(dl[s] * Ac[k]);
                st[k] = fmaf(A, st[k], dtv * Bc[s * 16 + k]);
                y = fmaf(st[k], Cc[s * 16 + k], y);
            }
            total += y;
        }
    }
    so[tid] = total * 0.2f;   // mean over S=5 of (y_f + y_b)
    __syncthreads();

    // ---- gate = silu(x @ W_g + b_g); o = scan_out @ W_out + b_out ----
    float g = b_g[tid];
    float o = b_out[tid];
    for (int d = 0; d < 128; ++d) {
        float xd = tok[0 * TS + d];
        float sd = so[d];
        g = fmaf(xd, W_g[d * 128 + tid], g);
        o = fmaf(sd, W_out[d * 128 + tid], o);
    }
    float gate = g / (1.0f + __expf(-g));
    float res = xv + gate * o;

    // ---- layernorm over D=128 ----
    red[tid] = res;
    red2[tid] = res * res;
    __syncthreads();
    for (int off = 64; off > 0; off >>= 1) {
        if (tid < off) {
            red[tid]  += red[tid + off];
            red2[tid] += red2[tid + off];
        }
        __syncthreads();
    }
    float mu  = red[0] * (1.0f / 128.0f);
    float var = red2[0] * (1.0f / 128.0f) - mu * mu;
    float outv = (res - mu) * rsqrtf(var + LN_EPS) * ln_g[tid] + ln_b[tid];
    out[(size_t)n * D_MODEL + tid] = outv;
}

// ---------------------------------------------------------------------------
extern "C" void kernel_launch(void* const* d_in, const int* in_sizes, int n_in,
                              void* d_out, int out_size, void* d_ws, size_t ws_size,
                              hipStream_t stream) {
    const float* x          = (const float*)d_in[0];
    const int*   edge_index = (const int*)  d_in[1];
    const int*   edge_type  = (const int*)  d_in[2];
    const int*   perms      = (const int*)  d_in[3];
    const float* rel_table  = (const float*)d_in[4];
    const float* log_A      = (const float*)d_in[5];
    const float* W_B        = (const float*)d_in[6];
    const float* W_C        = (const float*)d_in[7];
    const float* W_delta    = (const float*)d_in[8];
    const float* b_delta    = (const float*)d_in[9];
    const float* W_g        = (const float*)d_in[10];
    const float* b_g        = (const float*)d_in[11];
    const float* W_out      = (const float*)d_in[12];
    const float* b_out      = (const float*)d_in[13];
    const float* ln_g       = (const float*)d_in[14];
    const float* ln_b       = (const float*)d_in[15];

    float* seg = (float*)d_ws;                                    // [N,4,D]
    float* deg = seg + (size_t)N_NODES * 4 * D_MODEL;             // [N,4]
    size_t zero_bytes = ((size_t)N_NODES * 4 * D_MODEL + (size_t)N_NODES * 4) * sizeof(float);
    hipMemsetAsync(d_ws, 0, zero_bytes, stream);

    int total_threads = 4 * P_EDGES * 32;
    int blocks = (total_threads + 255) / 256;
    tokenize_scatter<<<blocks, 256, 0, stream>>>(
        x, edge_index, edge_type, perms, rel_table, seg, deg);

    node_update<<<N_NODES, 128, 0, stream>>>(
        x, seg, deg, log_A, W_B, W_C, W_delta, b_delta,
        W_g, b_g, W_out, b_out, ln_g, ln_b, (float*)d_out);
}

// Round 2
// 401.094 us; speedup vs baseline: 2.0482x; 2.0482x over previous
//
#include <hip/hip_runtime.h>
#include <math.h>

#define N_NODES 10000
#define D_MODEL 128
#define K_STATE 16
#define S_LEN 5
#define E_EDGES 320000
#define P_EDGES 80000   // E/(S-1)
#define LN_EPS 1e-5f
#define NBUCK 40960     // 1024*40 >= N_NODES*4

// ---------------------------------------------------------------------------
// Kernel 1: count edges per (dst,step) bucket.
// ---------------------------------------------------------------------------
__global__ __launch_bounds__(256) void csr_count(
    const int* __restrict__ edge_index,
    const int* __restrict__ perms,
    int* __restrict__ cnt)
{
    int gid = blockIdx.x * blockDim.x + threadIdx.x;
    if (gid >= 4 * P_EDGES) return;
    int s = gid / P_EDGES;
    int e = perms[gid];
    int dst = edge_index[E_EDGES + e];
    atomicAdd(&cnt[dst * 4 + s], 1);
}

// ---------------------------------------------------------------------------
// Kernel 2: exclusive prefix sum over NBUCK counters (single block).
// Writes off[] and cursor[] (same values).
// ---------------------------------------------------------------------------
__global__ __launch_bounds__(1024) void csr_scan(
    const int* __restrict__ cnt,
    int* __restrict__ off,
    int* __restrict__ cursor)
{
    __shared__ int ssum[1024];
    const int t = threadIdx.x;
    const int CH = NBUCK / 1024;   // 40
    const int base = t * CH;

    int sum = 0;
    for (int i = 0; i < CH; ++i) sum += cnt[base + i];
    ssum[t] = sum;
    __syncthreads();
    for (int o = 1; o < 1024; o <<= 1) {
        int v = (t >= o) ? ssum[t - o] : 0;
        __syncthreads();
        ssum[t] += v;
        __syncthreads();
    }
    int run = ssum[t] - sum;   // exclusive base for this chunk
    for (int i = 0; i < CH; ++i) {
        off[base + i] = run;
        cursor[base + i] = run;
        run += cnt[base + i];
    }
}

// ---------------------------------------------------------------------------
// Kernel 3: fill CSR payload (src, edge_type) per bucket.
// ---------------------------------------------------------------------------
__global__ __launch_bounds__(256) void csr_fill(
    const int* __restrict__ edge_index,
    const int* __restrict__ edge_type,
    const int* __restrict__ perms,
    int* __restrict__ cursor,
    int2* __restrict__ csr)
{
    int gid = blockIdx.x * blockDim.x + threadIdx.x;
    if (gid >= 4 * P_EDGES) return;
    int s = gid / P_EDGES;
    int e = perms[gid];
    int src = edge_index[e];
    int dst = edge_index[E_EDGES + e];
    int et  = edge_type[e];
    int pos = atomicAdd(&cursor[dst * 4 + s], 1);
    csr[pos] = make_int2(src, et);
}

// ---------------------------------------------------------------------------
// Kernel 4: per-node compute (gather fused). Block = 128 threads = one node.
// ---------------------------------------------------------------------------
__global__ __launch_bounds__(128) void node_update(
    const float* __restrict__ x,
    const int* __restrict__ off,
    const int2* __restrict__ csr,
    const float* __restrict__ rel_table,
    const float* __restrict__ log_A,
    const float* __restrict__ W_B,
    const float* __restrict__ W_C,
    const float* __restrict__ W_delta,
    const float* __restrict__ b_delta,
    const float* __restrict__ W_g,
    const float* __restrict__ b_g,
    const float* __restrict__ W_out,
    const float* __restrict__ b_out,
    const float* __restrict__ ln_g,
    const float* __restrict__ ln_b,
    float* __restrict__ out)
{
    const int n = blockIdx.x;
    const int tid = threadIdx.x;      // 0..127
    const int TS = 132;               // padded LDS stride

    __shared__ float tok[5 * 132];
    __shared__ float dlt[5 * 132];
    __shared__ float Bc[5 * 16];
    __shared__ float Cc[5 * 16];
    __shared__ float so[128];
    __shared__ float red[128];
    __shared__ float red2[128];

    // ---- gather neighbor tokens from CSR ----
    float xv = x[(size_t)n * D_MODEL + tid];
    tok[0 * TS + tid] = xv;

    int o0 = off[n * 4 + 0];
    int o1 = off[n * 4 + 1];
    int o2 = off[n * 4 + 2];
    int o3 = off[n * 4 + 3];
    int o4 = off[n * 4 + 4];
    float a0 = 0.f, a1 = 0.f, a2 = 0.f, a3 = 0.f;
    for (int j = o0; j < o4; ++j) {
        int2 se = csr[j];
        float v = x[(size_t)se.x * D_MODEL + tid]
                + rel_table[(size_t)se.y * D_MODEL + tid];
        if (j < o1) a0 += v;
        else if (j < o2) a1 += v;
        else if (j < o3) a2 += v;
        else a3 += v;
    }
    tok[1 * TS + tid] = a0 / fmaxf((float)(o1 - o0), 1.f);
    tok[2 * TS + tid] = a1 / fmaxf((float)(o2 - o1), 1.f);
    tok[3 * TS + tid] = a2 / fmaxf((float)(o3 - o2), 1.f);
    tok[4 * TS + tid] = a3 / fmaxf((float)(o4 - o3), 1.f);
    __syncthreads();

    // ---- deltas = softplus(tokens @ W_delta + b_delta) ----
    float z[5];
    {
        float bd = b_delta[tid];
        #pragma unroll
        for (int s = 0; s < 5; ++s) z[s] = bd;
        for (int d = 0; d < 128; ++d) {
            float w = W_delta[d * 128 + tid];
            #pragma unroll
            for (int s = 0; s < 5; ++s) z[s] = fmaf(tok[s * TS + d], w, z[s]);
        }
        #pragma unroll
        for (int s = 0; s < 5; ++s) {
            float zz = z[s];
            dlt[s * TS + tid] = (zz > 15.0f) ? zz : log1pf(__expf(zz));
        }
    }

    // ---- B = tokens @ W_B, C = tokens @ W_C ----
    for (int idx = tid; idx < 160; idx += 128) {
        int m = idx >= 80;
        int r = idx - m * 80;
        int s = r >> 4;
        int k = r & 15;
        const float* W = m ? W_C : W_B;
        float acc = 0.0f;
        for (int d = 0; d < 128; ++d)
            acc = fmaf(tok[s * TS + d], W[d * K_STATE + k], acc);
        if (m) Cc[s * 16 + k] = acc; else Bc[s * 16 + k] = acc;
    }
    __syncthreads();

    // ---- selective scan, forward + backward ----
    float Ac[16];
    #pragma unroll
    for (int k = 0; k < 16; ++k) Ac[k] = -__expf(log_A[tid * 16 + k]);
    float tv[5], dl[5];
    #pragma unroll
    for (int s = 0; s < 5; ++s) {
        tv[s] = tok[s * TS + tid];
        dl[s] = dlt[s * TS + tid];
    }

    float total = 0.0f;
    {   // forward
        float st[16];
        #pragma unroll
        for (int k = 0; k < 16; ++k) st[k] = 0.0f;
        #pragma unroll
        for (int s = 0; s < 5; ++s) {
            float dtv = dl[s] * tv[s];
            float y = 0.0f;
            #pragma unroll
            for (int k = 0; k < 16; ++k) {
                float A = __expf(dl[s] * Ac[k]);
                st[k] = fmaf(A, st[k], dtv * Bc[s * 16 + k]);
                y = fmaf(st[k], Cc[s * 16 + k], y);
            }
            total += y;
        }
    }
    {   // backward
        float st[16];
        #pragma unroll
        for (int k = 0; k < 16; ++k) st[k] = 0.0f;
        #pragma unroll
        for (int s = 4; s >= 0; --s) {
            float dtv = dl[s] * tv[s];
            float y = 0.0f;
            #pragma unroll
            for (int k = 0; k < 16; ++k) {
                float A = __expf(dl[s] * Ac[k]);
                st[k] = fmaf(A, st[k], dtv * Bc[s * 16 + k]);
                y = fmaf(st[k], Cc[s * 16 + k], y);
            }
            total += y;
        }
    }
    so[tid] = total * 0.2f;
    __syncthreads();

    // ---- gate & output projection ----
    float g = b_g[tid];
    float o = b_out[tid];
    for (int d = 0; d < 128; ++d) {
        float xd = tok[0 * TS + d];
        float sd = so[d];
        g = fmaf(xd, W_g[d * 128 + tid], g);
        o = fmaf(sd, W_out[d * 128 + tid], o);
    }
    float gate = g / (1.0f + __expf(-g));
    float res = xv + gate * o;

    // ---- layernorm ----
    red[tid] = res;
    red2[tid] = res * res;
    __syncthreads();
    for (int offr = 64; offr > 0; offr >>= 1) {
        if (tid < offr) {
            red[tid]  += red[tid + offr];
            red2[tid] += red2[tid + offr];
        }
        __syncthreads();
    }
    float mu  = red[0] * (1.0f / 128.0f);
    float var = red2[0] * (1.0f / 128.0f) - mu * mu;
    float outv = (res - mu) * rsqrtf(var + LN_EPS) * ln_g[tid] + ln_b[tid];
    out[(size_t)n * D_MODEL + tid] = outv;
}

// ---------------------------------------------------------------------------
extern "C" void kernel_launch(void* const* d_in, const int* in_sizes, int n_in,
                              void* d_out, int out_size, void* d_ws, size_t ws_size,
                              hipStream_t stream) {
    const float* x          = (const float*)d_in[0];
    const int*   edge_index = (const int*)  d_in[1];
    const int*   edge_type  = (const int*)  d_in[2];
    const int*   perms      = (const int*)  d_in[3];
    const float* rel_table  = (const float*)d_in[4];
    const float* log_A      = (const float*)d_in[5];
    const float* W_B        = (const float*)d_in[6];
    const float* W_C        = (const float*)d_in[7];
    const float* W_delta    = (const float*)d_in[8];
    const float* b_delta    = (const float*)d_in[9];
    const float* W_g        = (const float*)d_in[10];
    const float* b_g        = (const float*)d_in[11];
    const float* W_out      = (const float*)d_in[12];
    const float* b_out      = (const float*)d_in[13];
    const float* ln_g       = (const float*)d_in[14];
    const float* ln_b       = (const float*)d_in[15];

    int* cnt    = (int*)d_ws;                 // [NBUCK]
    int* offb   = cnt + NBUCK;                // [NBUCK]
    int* cursor = offb + NBUCK;               // [NBUCK]
    int2* csr   = (int2*)(cursor + NBUCK);    // [4*P_EDGES]

    hipMemsetAsync(cnt, 0, NBUCK * sizeof(int), stream);

    int nthreads = 4 * P_EDGES;
    int blocks = (nthreads + 255) / 256;
    csr_count<<<blocks, 256, 0, stream>>>(edge_index, perms, cnt);
    csr_scan<<<1, 1024, 0, stream>>>(cnt, offb, cursor);
    csr_fill<<<blocks, 256, 0, stream>>>(edge_index, edge_type, perms, cursor, csr);

    node_update<<<N_NODES, 128, 0, stream>>>(
        x, offb, csr, rel_table, log_A, W_B, W_C, W_delta, b_delta,
        W_g, b_g, W_out, b_out, ln_g, ln_b, (float*)d_out);
}

// Round 3
// 271.044 us; speedup vs baseline: 3.0309x; 1.4798x over previous
//
#include <hip/hip_runtime.h>
#include <hip/hip_bf16.h>
#include <math.h>

#define N_NODES 10000
#define D_MODEL 128
#define E_EDGES 320000
#define P_EDGES 80000
#define LN_EPS 1e-5f
#define NBUCK 40960        // padded 4*N for the 1024-thread scan
#define M_ROWS 50000       // 5*N token rows
#define M_PAD  50048       // 782 * 64
#define NPAD   320         // 288 cols padded to 5*64

typedef __attribute__((ext_vector_type(8))) short bf16x8;
typedef __attribute__((ext_vector_type(4))) float f32x4;

__device__ __forceinline__ unsigned short f2bf(float f) {
    __hip_bfloat16 h = __float2bfloat16(f);
    return *reinterpret_cast<unsigned short*>(&h);
}
__device__ __forceinline__ float bf2f(unsigned short u) {
    return __uint_as_float(((unsigned int)u) << 16);
}

// ---------------------------------------------------------------------------
// Pack weights bf16 into B-fragment-friendly layout:
// Bp[((k>>3)*NPAD + n)*8 + (k&7)] ; cols: 0-127 W_delta, 128-143 W_B,
// 144-159 W_C, 160-287 W_g, 288-319 zero pad.
// ---------------------------------------------------------------------------
__global__ __launch_bounds__(256) void prep_weights(
    const float* __restrict__ Wd, const float* __restrict__ Wb,
    const float* __restrict__ Wc, const float* __restrict__ Wg,
    unsigned short* __restrict__ Bp)
{
    int gid = blockIdx.x * 256 + threadIdx.x;
    if (gid >= 128 * NPAD) return;
    int k = gid / NPAD, n = gid - (gid / NPAD) * NPAD;
    float v = 0.f;
    if (n < 128)      v = Wd[k * 128 + n];
    else if (n < 144) v = Wb[k * 16 + (n - 128)];
    else if (n < 160) v = Wc[k * 16 + (n - 144)];
    else if (n < 288) v = Wg[k * 128 + (n - 160)];
    Bp[((size_t)(k >> 3) * NPAD + n) * 8 + (k & 7)] = f2bf(v);
}

// ---------------------------------------------------------------------------
__global__ __launch_bounds__(256) void csr_count(
    const int* __restrict__ edge_index, const int* __restrict__ perms,
    int* __restrict__ cnt)
{
    int gid = blockIdx.x * blockDim.x + threadIdx.x;
    if (gid >= 4 * P_EDGES) return;
    int s = gid / P_EDGES;
    int e = perms[gid];
    int dst = edge_index[E_EDGES + e];
    atomicAdd(&cnt[dst * 4 + s], 1);
}

// Coalesced scan: thread t owns buckets {t, t+1024, ...} ranked consecutively.
// Any consistent total order is a valid CSR; gather uses off[b]..off[b]+cnt[b].
__global__ __launch_bounds__(1024) void csr_scan(
    const int* __restrict__ cnt, int* __restrict__ off, int* __restrict__ cursor)
{
    __shared__ int ssum[1024];
    const int t = threadIdx.x;
    int vals[40];
    int sum = 0;
    #pragma unroll 8
    for (int i = 0; i < 40; ++i) { vals[i] = cnt[t + 1024 * i]; sum += vals[i]; }
    ssum[t] = sum;
    __syncthreads();
    for (int o = 1; o < 1024; o <<= 1) {
        int v = (t >= o) ? ssum[t - o] : 0;
        __syncthreads();
        ssum[t] += v;
        __syncthreads();
    }
    int run = ssum[t] - sum;
    #pragma unroll 8
    for (int i = 0; i < 40; ++i) {
        off[t + 1024 * i] = run;
        cursor[t + 1024 * i] = run;
        run += vals[i];
    }
}

__global__ __launch_bounds__(256) void csr_fill(
    const int* __restrict__ edge_index, const int* __restrict__ edge_type,
    const int* __restrict__ perms, int* __restrict__ cursor,
    int2* __restrict__ csr)
{
    int gid = blockIdx.x * blockDim.x + threadIdx.x;
    if (gid >= 4 * P_EDGES) return;
    int s = gid / P_EDGES;
    int e = perms[gid];
    int src = edge_index[e];
    int dst = edge_index[E_EDGES + e];
    int et  = edge_type[e];
    int pos = atomicAdd(&cursor[dst * 4 + s], 1);
    csr[pos] = make_int2(src, et);
}

// ---------------------------------------------------------------------------
// Gather: one wave per (node, step) bucket; lane handles dims 2*lane, 2*lane+1.
// Writes bf16 tokens [M_PAD, 128], row = n*5+s (s=0 is x itself).
// ---------------------------------------------------------------------------
__global__ __launch_bounds__(256) void gather_tokens(
    const float* __restrict__ x,
    const int* __restrict__ off, const int* __restrict__ cnt,
    const int2* __restrict__ csr, const float* __restrict__ rel,
    unsigned short* __restrict__ tokens)
{
    int n = blockIdx.x;
    int w = threadIdx.x >> 6, lane = threadIdx.x & 63;
    int b = n * 4 + w;
    int j0 = off[b], c = cnt[b];
    const float2* x2 = (const float2*)x;
    const float2* r2 = (const float2*)rel;
    float ax = 0.f, ay = 0.f;
    for (int j = j0; j < j0 + c; ++j) {
        int2 se = csr[j];
        float2 xv = x2[(size_t)se.x * 64 + lane];
        float2 rv = r2[(size_t)se.y * 64 + lane];
        ax += xv.x + rv.x;
        ay += xv.y + rv.y;
    }
    float inv = 1.f / fmaxf((float)c, 1.f);
    unsigned int pack = (unsigned int)f2bf(ax * inv) | ((unsigned int)f2bf(ay * inv) << 16);
    ((unsigned int*)tokens)[((size_t)n * 5 + w + 1) * 64 + lane] = pack;
    if (w == 0) {
        float2 xv = x2[(size_t)n * 64 + lane];
        unsigned int p0 = (unsigned int)f2bf(xv.x) | ((unsigned int)f2bf(xv.y) << 16);
        ((unsigned int*)tokens)[((size_t)n * 5) * 64 + lane] = p0;
    }
}

// ---------------------------------------------------------------------------
// MFMA GEMM: Z[M,288] = tokens @ Wcat. Block 256 = 4 waves, tile 64(M)x64(N).
// A frag straight from global (16B/lane, contiguous); B from packed Bp.
// Epilogue routes: cols<128 -> softplus(z+b_delta) -> delta bf16;
// 128..159 -> bc bf16; 160..287 -> (rows r%5==0 only) g = z+b_g bf16.
// ---------------------------------------------------------------------------
__global__ __launch_bounds__(256) void mfma_gemm(
    const unsigned short* __restrict__ tokens,
    const unsigned short* __restrict__ Bp,
    const float* __restrict__ b_delta, const float* __restrict__ b_g,
    unsigned short* __restrict__ delta,
    unsigned short* __restrict__ bc,
    unsigned short* __restrict__ g)
{
    int m0 = blockIdx.x * 64, n0 = blockIdx.y * 64;
    int wv = threadIdx.x >> 6, lane = threadIdx.x & 63;
    int quad = lane >> 4, l16 = lane & 15;

    f32x4 acc[4] = {{0,0,0,0},{0,0,0,0},{0,0,0,0},{0,0,0,0}};
    const unsigned short* arow = tokens + (size_t)(m0 + wv * 16 + l16) * 128 + quad * 8;
    #pragma unroll
    for (int kc = 0; kc < 128; kc += 32) {
        bf16x8 a = *(const bf16x8*)(arow + kc);
        #pragma unroll
        for (int t = 0; t < 4; ++t) {
            bf16x8 b = *(const bf16x8*)(Bp + ((size_t)(kc / 8 + quad) * NPAD + n0 + 16 * t + l16) * 8);
            acc[t] = __builtin_amdgcn_mfma_f32_16x16x32_bf16(a, b, acc[t], 0, 0, 0);
        }
    }

    int rbase = m0 + wv * 16 + quad * 4;
    #pragma unroll
    for (int t = 0; t < 4; ++t) {
        int c = n0 + 16 * t + l16;
        #pragma unroll
        for (int reg = 0; reg < 4; ++reg) {
            int r = rbase + reg;
            if (r >= M_ROWS) continue;
            float v = acc[t][reg];
            if (c < 128) {
                float z = v + b_delta[c];
                float d = (z > 15.f) ? z : log1pf(__expf(z));
                delta[(size_t)r * 128 + c] = f2bf(d);
            } else if (c < 160) {
                bc[(size_t)r * 32 + (c - 128)] = f2bf(v);
            } else if (c < 288) {
                int rq = r / 5;
                if (r - rq * 5 == 0)
                    g[(size_t)rq * 128 + (c - 160)] = f2bf(v + b_g[c - 160]);
            }
        }
    }
}

// ---------------------------------------------------------------------------
// Scan + output projection + gate + layernorm. Block 128 = one node.
// ---------------------------------------------------------------------------
__global__ __launch_bounds__(128) void scan_final(
    const float* __restrict__ x,
    const unsigned short* __restrict__ tokens,
    const unsigned short* __restrict__ delta,
    const unsigned short* __restrict__ bcbuf,
    const unsigned short* __restrict__ gbuf,
    const float* __restrict__ log_A,
    const float* __restrict__ W_out, const float* __restrict__ b_out,
    const float* __restrict__ ln_g, const float* __restrict__ ln_b,
    float* __restrict__ out)
{
    int n = blockIdx.x, tid = threadIdx.x;
    __shared__ __align__(16) float BC[160];   // [s][0..15]=B, [s][16..31]=C
    __shared__ __align__(16) float so[128];
    __shared__ float red[128], red2[128];

    for (int idx = tid; idx < 160; idx += 128) {
        int s = idx >> 5, q = idx & 31;
        BC[idx] = bf2f(bcbuf[((size_t)n * 5 + s) * 32 + q]);
    }

    float tv[5], dl[5];
    #pragma unroll
    for (int s = 0; s < 5; ++s) {
        tv[s] = bf2f(tokens[((size_t)n * 5 + s) * 128 + tid]);
        dl[s] = bf2f(delta[((size_t)n * 5 + s) * 128 + tid]);
    }
    float Ac[16];
    {
        const float4* la = (const float4*)(log_A + tid * 16);
        #pragma unroll
        for (int q = 0; q < 4; ++q) {
            float4 lv = la[q];
            Ac[q * 4 + 0] = -__expf(lv.x);
            Ac[q * 4 + 1] = -__expf(lv.y);
            Ac[q * 4 + 2] = -__expf(lv.z);
            Ac[q * 4 + 3] = -__expf(lv.w);
        }
    }
    __syncthreads();

    float total = 0.f;
    {   // forward
        float st[16];
        #pragma unroll
        for (int k = 0; k < 16; ++k) st[k] = 0.f;
        #pragma unroll
        for (int s = 0; s < 5; ++s) {
            float dtv = dl[s] * tv[s];
            float y = 0.f;
            #pragma unroll
            for (int k = 0; k < 16; ++k) {
                float A = __expf(dl[s] * Ac[k]);
                st[k] = fmaf(A, st[k], dtv * BC[s * 32 + k]);
                y = fmaf(st[k], BC[s * 32 + 16 + k], y);
            }
            total += y;
        }
    }
    {   // backward
        float st[16];
        #pragma unroll
        for (int k = 0; k < 16; ++k) st[k] = 0.f;
        #pragma unroll
        for (int s = 4; s >= 0; --s) {
            float dtv = dl[s] * tv[s];
            float y = 0.f;
            #pragma unroll
            for (int k = 0; k < 16; ++k) {
                float A = __expf(dl[s] * Ac[k]);
                st[k] = fmaf(A, st[k], dtv * BC[s * 32 + k]);
                y = fmaf(st[k], BC[s * 32 + 16 + k], y);
            }
            total += y;
        }
    }
    so[tid] = total * 0.2f;
    float gl = bf2f(gbuf[(size_t)n * 128 + tid]);
    float gate = gl / (1.f + __expf(-gl));
    __syncthreads();

    float o = b_out[tid];
    for (int d = 0; d < 128; d += 4) {
        float4 sv = *(const float4*)&so[d];
        o = fmaf(sv.x, W_out[(d + 0) * 128 + tid], o);
        o = fmaf(sv.y, W_out[(d + 1) * 128 + tid], o);
        o = fmaf(sv.z, W_out[(d + 2) * 128 + tid], o);
        o = fmaf(sv.w, W_out[(d + 3) * 128 + tid], o);
    }
    float res = x[(size_t)n * 128 + tid] + gate * o;

    red[tid] = res; red2[tid] = res * res;
    __syncthreads();
    for (int offr = 64; offr > 0; offr >>= 1) {
        if (tid < offr) { red[tid] += red[tid + offr]; red2[tid] += red2[tid + offr]; }
        __syncthreads();
    }
    float mu  = red[0] * (1.f / 128.f);
    float var = red2[0] * (1.f / 128.f) - mu * mu;
    out[(size_t)n * 128 + tid] = (res - mu) * rsqrtf(var + LN_EPS) * ln_g[tid] + ln_b[tid];
}

// ---------------------------------------------------------------------------
extern "C" void kernel_launch(void* const* d_in, const int* in_sizes, int n_in,
                              void* d_out, int out_size, void* d_ws, size_t ws_size,
                              hipStream_t stream) {
    const float* x          = (const float*)d_in[0];
    const int*   edge_index = (const int*)  d_in[1];
    const int*   edge_type  = (const int*)  d_in[2];
    const int*   perms      = (const int*)  d_in[3];
    const float* rel_table  = (const float*)d_in[4];
    const float* log_A      = (const float*)d_in[5];
    const float* W_B        = (const float*)d_in[6];
    const float* W_C        = (const float*)d_in[7];
    const float* W_delta    = (const float*)d_in[8];
    const float* b_delta    = (const float*)d_in[9];
    const float* W_g        = (const float*)d_in[10];
    const float* b_g        = (const float*)d_in[11];
    const float* W_out      = (const float*)d_in[12];
    const float* b_out      = (const float*)d_in[13];
    const float* ln_g       = (const float*)d_in[14];
    const float* ln_b       = (const float*)d_in[15];

    char* ws = (char*)d_ws;
    int*  cnt    = (int*) (ws + 0);
    int*  offb   = (int*) (ws + 163840);
    int*  cursor = (int*) (ws + 327680);
    int2* csr    = (int2*)(ws + 491520);
    unsigned short* Bp     = (unsigned short*)(ws + 3051520);
    unsigned short* tokens = (unsigned short*)(ws + 3133440);
    unsigned short* delta  = (unsigned short*)(ws + 15945728);
    unsigned short* bc     = (unsigned short*)(ws + 28745728);
    unsigned short* g      = (unsigned short*)(ws + 31945728);

    hipMemsetAsync(cnt, 0, NBUCK * sizeof(int), stream);

    prep_weights<<<(128 * NPAD + 255) / 256, 256, 0, stream>>>(
        W_delta, W_B, W_C, W_g, Bp);

    int eb = (4 * P_EDGES + 255) / 256;
    csr_count<<<eb, 256, 0, stream>>>(edge_index, perms, cnt);
    csr_scan<<<1, 1024, 0, stream>>>(cnt, offb, cursor);
    csr_fill<<<eb, 256, 0, stream>>>(edge_index, edge_type, perms, cursor, csr);

    gather_tokens<<<N_NODES, 256, 0, stream>>>(
        x, offb, cnt, csr, rel_table, tokens);

    mfma_gemm<<<dim3(M_PAD / 64, NPAD / 64), 256, 0, stream>>>(
        tokens, Bp, b_delta, b_g, delta, bc, g);

    scan_final<<<N_NODES, 128, 0, stream>>>(
        x, tokens, delta, bc, g, log_A, W_out, b_out, ln_g, ln_b, (float*)d_out);
}

// Round 4
// 225.511 us; speedup vs baseline: 3.6429x; 1.2019x over previous
//
#include <hip/hip_runtime.h>
#include <hip/hip_bf16.h>
#include <math.h>

#define N_NODES 10000
#define D_MODEL 128
#define E_EDGES 320000
#define P_EDGES 80000
#define LN_EPS 1e-5f
#define NBUCK 40960        // padded 4*N buckets
#define CAP 40             // max edges kept per (node,step) bucket
#define M_ROWS 50000       // 5*N token rows
#define M_PAD  50048       // 782 * 64
#define NPAD   320         // 288 cols padded to 5*64

typedef __attribute__((ext_vector_type(8))) short bf16x8;
typedef __attribute__((ext_vector_type(4))) float f32x4;

__device__ __forceinline__ unsigned short f2bf(float f) {
    __hip_bfloat16 h = __float2bfloat16(f);
    return *reinterpret_cast<unsigned short*>(&h);
}
__device__ __forceinline__ float bf2f(unsigned short u) {
    return __uint_as_float(((unsigned int)u) << 16);
}

// ---------------------------------------------------------------------------
// Pack [W_delta|W_B|W_C|W_g] (cols 0..287, pad to 320) into B-frag layout.
// ---------------------------------------------------------------------------
__global__ __launch_bounds__(256) void prep_weights(
    const float* __restrict__ Wd, const float* __restrict__ Wb,
    const float* __restrict__ Wc, const float* __restrict__ Wg,
    unsigned short* __restrict__ Bp)
{
    int gid = blockIdx.x * 256 + threadIdx.x;
    if (gid >= 128 * NPAD) return;
    int k = gid / NPAD, n = gid - (gid / NPAD) * NPAD;
    float v = 0.f;
    if (n < 128)      v = Wd[k * 128 + n];
    else if (n < 144) v = Wb[k * 16 + (n - 128)];
    else if (n < 160) v = Wc[k * 16 + (n - 144)];
    else if (n < 288) v = Wg[k * 128 + (n - 160)];
    Bp[((size_t)(k >> 3) * NPAD + n) * 8 + (k & 7)] = f2bf(v);
}

__global__ __launch_bounds__(256) void prep_wout(
    const float* __restrict__ W_out, unsigned short* __restrict__ Wop)
{
    int gid = blockIdx.x * 256 + threadIdx.x;
    if (gid >= 128 * 128) return;
    int k = gid >> 7, n = gid & 127;
    Wop[((size_t)(k >> 3) * 128 + n) * 8 + (k & 7)] = f2bf(W_out[k * 128 + n]);
}

// ---------------------------------------------------------------------------
// One-pass CSR: bucket b = dst*4+s gets (src,et) at slots[b*CAP + pos].
// cnt[b] is the true degree (used as the mean denominator).
// ---------------------------------------------------------------------------
__global__ __launch_bounds__(256) void csr_build(
    const int* __restrict__ edge_index, const int* __restrict__ edge_type,
    const int* __restrict__ perms,
    int* __restrict__ cnt, int2* __restrict__ slots)
{
    int gid = blockIdx.x * blockDim.x + threadIdx.x;
    if (gid >= 4 * P_EDGES) return;
    int s = gid / P_EDGES;
    int e = perms[gid];
    int src = edge_index[e];
    int dst = edge_index[E_EDGES + e];
    int et  = edge_type[e];
    int b = dst * 4 + s;
    int pos = atomicAdd(&cnt[b], 1);
    if (pos < CAP) slots[(size_t)b * CAP + pos] = make_int2(src, et);
}

// ---------------------------------------------------------------------------
// Gather: one wave per (node,step) bucket; lane = 2 dims; 2 edges per iter.
// ---------------------------------------------------------------------------
__global__ __launch_bounds__(256) void gather_tokens(
    const float* __restrict__ x,
    const int* __restrict__ cnt, const int2* __restrict__ slots,
    const float* __restrict__ rel,
    unsigned short* __restrict__ tokens)
{
    int n = blockIdx.x;
    int w = threadIdx.x >> 6, lane = threadIdx.x & 63;
    int b = n * 4 + w;
    int c = cnt[b];
    int cc = min(c, CAP);
    const int2* sl = slots + (size_t)b * CAP;
    const float2* x2 = (const float2*)x;
    const float2* r2 = (const float2*)rel;
    float ax = 0.f, ay = 0.f;
    int j = 0;
    for (; j + 2 <= cc; j += 2) {
        int4 two = *(const int4*)(sl + j);
        float2 x0 = x2[(size_t)two.x * 64 + lane];
        float2 r0 = r2[(size_t)two.y * 64 + lane];
        float2 x1 = x2[(size_t)two.z * 64 + lane];
        float2 r1 = r2[(size_t)two.w * 64 + lane];
        ax += (x0.x + r0.x) + (x1.x + r1.x);
        ay += (x0.y + r0.y) + (x1.y + r1.y);
    }
    if (j < cc) {
        int2 se = sl[j];
        float2 xv = x2[(size_t)se.x * 64 + lane];
        float2 rv = r2[(size_t)se.y * 64 + lane];
        ax += xv.x + rv.x;
        ay += xv.y + rv.y;
    }
    float inv = 1.f / fmaxf((float)c, 1.f);
    unsigned int pack = (unsigned int)f2bf(ax * inv) | ((unsigned int)f2bf(ay * inv) << 16);
    ((unsigned int*)tokens)[((size_t)n * 5 + w + 1) * 64 + lane] = pack;
    if (w == 0) {
        float2 xv = x2[(size_t)n * 64 + lane];
        unsigned int p0 = (unsigned int)f2bf(xv.x) | ((unsigned int)f2bf(xv.y) << 16);
        ((unsigned int*)tokens)[((size_t)n * 5) * 64 + lane] = p0;
    }
}

// ---------------------------------------------------------------------------
// GEMM1: Z[M,288] = tokens @ Wcat. Epilogue -> delta (softplus), bc, g.
// ---------------------------------------------------------------------------
__global__ __launch_bounds__(256) void mfma_gemm(
    const unsigned short* __restrict__ tokens,
    const unsigned short* __restrict__ Bp,
    const float* __restrict__ b_delta, const float* __restrict__ b_g,
    unsigned short* __restrict__ delta,
    unsigned short* __restrict__ bc,
    unsigned short* __restrict__ g)
{
    int m0 = blockIdx.x * 64, n0 = blockIdx.y * 64;
    int wv = threadIdx.x >> 6, lane = threadIdx.x & 63;
    int quad = lane >> 4, l16 = lane & 15;

    f32x4 acc[4] = {{0,0,0,0},{0,0,0,0},{0,0,0,0},{0,0,0,0}};
    const unsigned short* arow = tokens + (size_t)(m0 + wv * 16 + l16) * 128 + quad * 8;
    #pragma unroll
    for (int kc = 0; kc < 128; kc += 32) {
        bf16x8 a = *(const bf16x8*)(arow + kc);
        #pragma unroll
        for (int t = 0; t < 4; ++t) {
            bf16x8 b = *(const bf16x8*)(Bp + ((size_t)(kc / 8 + quad) * NPAD + n0 + 16 * t + l16) * 8);
            acc[t] = __builtin_amdgcn_mfma_f32_16x16x32_bf16(a, b, acc[t], 0, 0, 0);
        }
    }

    int rbase = m0 + wv * 16 + quad * 4;
    #pragma unroll
    for (int t = 0; t < 4; ++t) {
        int c = n0 + 16 * t + l16;
        #pragma unroll
        for (int reg = 0; reg < 4; ++reg) {
            int r = rbase + reg;
            if (r >= M_ROWS) continue;
            float v = acc[t][reg];
            if (c < 128) {
                float z = v + b_delta[c];
                float d = (z > 15.f) ? z : log1pf(__expf(z));
                delta[(size_t)r * 128 + c] = f2bf(d);
            } else if (c < 160) {
                bc[(size_t)r * 32 + (c - 128)] = f2bf(v);
            } else if (c < 288) {
                int rq = r / 5;
                if (r - rq * 5 == 0)
                    g[(size_t)rq * 128 + (c - 160)] = f2bf(v + b_g[c - 160]);
            }
        }
    }
}

// ---------------------------------------------------------------------------
// Scan only: so[n,d] = mean_s(y_fwd + y_bwd) as bf16.
// ---------------------------------------------------------------------------
__global__ __launch_bounds__(128) void scan_so(
    const unsigned short* __restrict__ tokens,
    const unsigned short* __restrict__ delta,
    const unsigned short* __restrict__ bcbuf,
    const float* __restrict__ log_A,
    unsigned short* __restrict__ so)
{
    int n = blockIdx.x, tid = threadIdx.x;
    __shared__ __align__(16) float BC[160];

    for (int idx = tid; idx < 160; idx += 128) {
        int s = idx >> 5, q = idx & 31;
        BC[idx] = bf2f(bcbuf[((size_t)n * 5 + s) * 32 + q]);
    }
    float tv[5], dl[5];
    #pragma unroll
    for (int s = 0; s < 5; ++s) {
        tv[s] = bf2f(tokens[((size_t)n * 5 + s) * 128 + tid]);
        dl[s] = bf2f(delta[((size_t)n * 5 + s) * 128 + tid]);
    }
    float Ac[16];
    {
        const float4* la = (const float4*)(log_A + tid * 16);
        #pragma unroll
        for (int q = 0; q < 4; ++q) {
            float4 lv = la[q];
            Ac[q * 4 + 0] = -__expf(lv.x);
            Ac[q * 4 + 1] = -__expf(lv.y);
            Ac[q * 4 + 2] = -__expf(lv.z);
            Ac[q * 4 + 3] = -__expf(lv.w);
        }
    }
    __syncthreads();

    float total = 0.f;
    {
        float st[16];
        #pragma unroll
        for (int k = 0; k < 16; ++k) st[k] = 0.f;
        #pragma unroll
        for (int s = 0; s < 5; ++s) {
            float dtv = dl[s] * tv[s];
            float y = 0.f;
            #pragma unroll
            for (int k = 0; k < 16; ++k) {
                float A = __expf(dl[s] * Ac[k]);
                st[k] = fmaf(A, st[k], dtv * BC[s * 32 + k]);
                y = fmaf(st[k], BC[s * 32 + 16 + k], y);
            }
            total += y;
        }
    }
    {
        float st[16];
        #pragma unroll
        for (int k = 0; k < 16; ++k) st[k] = 0.f;
        #pragma unroll
        for (int s = 4; s >= 0; --s) {
            float dtv = dl[s] * tv[s];
            float y = 0.f;
            #pragma unroll
            for (int k = 0; k < 16; ++k) {
                float A = __expf(dl[s] * Ac[k]);
                st[k] = fmaf(A, st[k], dtv * BC[s * 32 + k]);
                y = fmaf(st[k], BC[s * 32 + 16 + k], y);
            }
            total += y;
        }
    }
    so[(size_t)n * 128 + tid] = f2bf(total * 0.2f);
}

// ---------------------------------------------------------------------------
// GEMM2: out = LN(x + silu(g) * (so @ W_out + b_out)). Tile 64 rows x 128.
// ---------------------------------------------------------------------------
__global__ __launch_bounds__(256) void out_gemm(
    const unsigned short* __restrict__ so,
    const unsigned short* __restrict__ Wop,
    const unsigned short* __restrict__ gbuf,
    const float* __restrict__ x,
    const float* __restrict__ b_out,
    const float* __restrict__ ln_g, const float* __restrict__ ln_b,
    float* __restrict__ out)
{
    int m0 = blockIdx.x * 64;
    int tid = threadIdx.x;
    int wv = tid >> 6, lane = tid & 63;
    int quad = lane >> 4, l16 = lane & 15;

    __shared__ float res[64 * 132];
    __shared__ float pmu[64][4];
    __shared__ float pv2[64][4];
    __shared__ float muA[64], rstdA[64];

    f32x4 acc[8] = {{0,0,0,0},{0,0,0,0},{0,0,0,0},{0,0,0,0},
                    {0,0,0,0},{0,0,0,0},{0,0,0,0},{0,0,0,0}};
    const unsigned short* arow = so + (size_t)(m0 + wv * 16 + l16) * 128 + quad * 8;
    #pragma unroll
    for (int kc = 0; kc < 128; kc += 32) {
        bf16x8 a = *(const bf16x8*)(arow + kc);
        #pragma unroll
        for (int t = 0; t < 8; ++t) {
            bf16x8 b = *(const bf16x8*)(Wop + ((size_t)(kc / 8 + quad) * 128 + 16 * t + l16) * 8);
            acc[t] = __builtin_amdgcn_mfma_f32_16x16x32_bf16(a, b, acc[t], 0, 0, 0);
        }
    }

    int lrow = wv * 16 + quad * 4;
    #pragma unroll
    for (int t = 0; t < 8; ++t) {
        int c = 16 * t + l16;
        #pragma unroll
        for (int reg = 0; reg < 4; ++reg) {
            int r = m0 + lrow + reg;
            float v = 0.f;
            if (r < N_NODES) {
                float o = acc[t][reg] + b_out[c];
                float gl = bf2f(gbuf[(size_t)r * 128 + c]);
                float gate = gl / (1.f + __expf(-gl));
                v = x[(size_t)r * 128 + c] + gate * o;
            }
            res[(lrow + reg) * 132 + c] = v;
        }
    }
    __syncthreads();

    {   // per-row partial sums; cols strided by 4 (2-way LDS aliasing = free)
        int row = tid >> 2, q = tid & 3;
        float s = 0.f, s2 = 0.f;
        #pragma unroll
        for (int i = 0; i < 32; ++i) {
            float v = res[row * 132 + q + 4 * i];
            s += v; s2 += v * v;
        }
        pmu[row][q] = s; pv2[row][q] = s2;
    }
    __syncthreads();
    if (tid < 64) {
        float s  = pmu[tid][0] + pmu[tid][1] + pmu[tid][2] + pmu[tid][3];
        float s2 = pv2[tid][0] + pv2[tid][1] + pv2[tid][2] + pv2[tid][3];
        float mu = s * (1.f / 128.f);
        float var = s2 * (1.f / 128.f) - mu * mu;
        muA[tid] = mu;
        rstdA[tid] = rsqrtf(var + LN_EPS);
    }
    __syncthreads();
    #pragma unroll
    for (int i = 0; i < 32; ++i) {
        int idx = i * 256 + tid;
        int row = idx >> 7, c = idx & 127;
        int r = m0 + row;
        if (r < N_NODES)
            out[(size_t)r * 128 + c] =
                (res[row * 132 + c] - muA[row]) * rstdA[row] * ln_g[c] + ln_b[c];
    }
}

// ---------------------------------------------------------------------------
extern "C" void kernel_launch(void* const* d_in, const int* in_sizes, int n_in,
                              void* d_out, int out_size, void* d_ws, size_t ws_size,
                              hipStream_t stream) {
    const float* x          = (const float*)d_in[0];
    const int*   edge_index = (const int*)  d_in[1];
    const int*   edge_type  = (const int*)  d_in[2];
    const int*   perms      = (const int*)  d_in[3];
    const float* rel_table  = (const float*)d_in[4];
    const float* log_A      = (const float*)d_in[5];
    const float* W_B        = (const float*)d_in[6];
    const float* W_C        = (const float*)d_in[7];
    const float* W_delta    = (const float*)d_in[8];
    const float* b_delta    = (const float*)d_in[9];
    const float* W_g        = (const float*)d_in[10];
    const float* b_g        = (const float*)d_in[11];
    const float* W_out      = (const float*)d_in[12];
    const float* b_out      = (const float*)d_in[13];
    const float* ln_g       = (const float*)d_in[14];
    const float* ln_b       = (const float*)d_in[15];

    char* ws = (char*)d_ws;
    int*            cnt    = (int*)           (ws + 0);          // 163840 B
    unsigned short* Bp     = (unsigned short*)(ws + 163840);     // 81920 B
    unsigned short* Wop    = (unsigned short*)(ws + 245760);     // 32768 B
    unsigned short* tokens = (unsigned short*)(ws + 278528);     // 12812288 B
    unsigned short* g      = (unsigned short*)(ws + 13090816);   // 2560000 B
    unsigned short* so     = (unsigned short*)(ws + 15650816);   // 2572288 B (10048 rows)
    unsigned short* bc     = (unsigned short*)(ws + 18223104);   // 3203072 B
    // union region: slots (read before gemm1) aliased with delta (written by gemm1)
    int2*           slots  = (int2*)          (ws + 21426176);   // 40960*40*8 = 13107200 B
    unsigned short* delta  = (unsigned short*)(ws + 21426176);   // 12812288 B

    hipMemsetAsync(cnt, 0, NBUCK * sizeof(int), stream);

    prep_weights<<<(128 * NPAD + 255) / 256, 256, 0, stream>>>(
        W_delta, W_B, W_C, W_g, Bp);
    prep_wout<<<64, 256, 0, stream>>>(W_out, Wop);

    csr_build<<<(4 * P_EDGES + 255) / 256, 256, 0, stream>>>(
        edge_index, edge_type, perms, cnt, slots);

    gather_tokens<<<N_NODES, 256, 0, stream>>>(
        x, cnt, slots, rel_table, tokens);

    mfma_gemm<<<dim3(M_PAD / 64, NPAD / 64), 256, 0, stream>>>(
        tokens, Bp, b_delta, b_g, delta, bc, g);

    scan_so<<<N_NODES, 128, 0, stream>>>(
        tokens, delta, bc, log_A, so);

    out_gemm<<<(N_NODES + 63) / 64, 256, 0, stream>>>(
        so, Wop, g, x, b_out, ln_g, ln_b, (float*)d_out);
}

// Round 5
// 204.945 us; speedup vs baseline: 4.0085x; 1.1004x over previous
//
#include <hip/hip_runtime.h>
#include <hip/hip_bf16.h>
#include <math.h>

#define N_NODES 10000
#define D_MODEL 128
#define E_EDGES 320000
#define P_EDGES 80000
#define R_REL 200
#define LN_EPS 1e-5f
#define NBUCK 40960        // 4*N padded
#define CAP 32             // slots per bucket (Poisson(8): never exceeded)
#define M_ROWS 50000
#define M_PAD  50048       // 782*64
#define NPAD   320         // 288 cols padded

typedef __attribute__((ext_vector_type(8))) short bf16x8;
typedef __attribute__((ext_vector_type(4))) float f32x4;

__device__ __forceinline__ unsigned short f2bf(float f) {
    __hip_bfloat16 h = __float2bfloat16(f);
    return *reinterpret_cast<unsigned short*>(&h);
}
__device__ __forceinline__ float bf2f(unsigned int u) {
    return __uint_as_float(u << 16);
}

// ---------------------------------------------------------------------------
// prep_all: pack Wcat + W_out into B-frag layout, convert x/rel to bf16,
// zero bucket counters. One dispatch.
// Segments: [0,40960) Bp | [40960,57344) Wop | [57344,98304) cnt |
//           [98304,123904) rel_bf | [123904,1403904) x_bf
// ---------------------------------------------------------------------------
__global__ __launch_bounds__(256) void prep_all(
    const float* __restrict__ Wd, const float* __restrict__ Wb,
    const float* __restrict__ Wc, const float* __restrict__ Wg,
    const float* __restrict__ W_out,
    const float* __restrict__ x, const float* __restrict__ rel,
    unsigned short* __restrict__ Bp, unsigned short* __restrict__ Wop,
    unsigned short* __restrict__ x_bf, unsigned short* __restrict__ rel_bf,
    int* __restrict__ cnt)
{
    int gid = blockIdx.x * 256 + threadIdx.x;
    if (gid < 40960) {
        int k = gid / NPAD, n = gid - (gid / NPAD) * NPAD;
        float v = 0.f;
        if (n < 128)      v = Wd[k * 128 + n];
        else if (n < 144) v = Wb[k * 16 + (n - 128)];
        else if (n < 160) v = Wc[k * 16 + (n - 144)];
        else if (n < 288) v = Wg[k * 128 + (n - 160)];
        Bp[((size_t)(k >> 3) * NPAD + n) * 8 + (k & 7)] = f2bf(v);
    } else if (gid < 57344) {
        int i = gid - 40960;
        int k = i >> 7, n = i & 127;
        Wop[((size_t)(k >> 3) * 128 + n) * 8 + (k & 7)] = f2bf(W_out[k * 128 + n]);
    } else if (gid < 98304) {
        cnt[gid - 57344] = 0;
    } else if (gid < 123904) {
        int i = gid - 98304;
        rel_bf[i] = f2bf(rel[i]);
    } else if (gid < 123904 + N_NODES * D_MODEL) {
        int i = gid - 123904;
        x_bf[i] = f2bf(x[i]);
    }
}

// ---------------------------------------------------------------------------
// One-pass CSR into fixed-capacity bucket slots.
// ---------------------------------------------------------------------------
__global__ __launch_bounds__(256) void csr_build(
    const int* __restrict__ edge_index, const int* __restrict__ edge_type,
    const int* __restrict__ perms,
    int* __restrict__ cnt, int2* __restrict__ slots)
{
    int gid = blockIdx.x * blockDim.x + threadIdx.x;
    if (gid >= 4 * P_EDGES) return;
    int s = gid / P_EDGES;
    int e = perms[gid];
    int src = edge_index[e];
    int dst = edge_index[E_EDGES + e];
    int et  = edge_type[e];
    int b = dst * 4 + s;
    int pos = atomicAdd(&cnt[b], 1);
    if (pos < CAP) slots[(size_t)b * CAP + pos] = make_int2(src, et);
}

// ---------------------------------------------------------------------------
// Gather (bf16 inputs): one wave per bucket; lane = 2 dims; 2 edges/iter.
// ---------------------------------------------------------------------------
__global__ __launch_bounds__(256) void gather_tokens(
    const unsigned short* __restrict__ x_bf,
    const int* __restrict__ cnt, const int2* __restrict__ slots,
    const unsigned short* __restrict__ rel_bf,
    unsigned short* __restrict__ tokens)
{
    int n = blockIdx.x;
    int w = threadIdx.x >> 6, lane = threadIdx.x & 63;
    int b = n * 4 + w;
    int c = cnt[b];
    int cc = c < CAP ? c : CAP;
    const int2* sl = slots + (size_t)b * CAP;
    const unsigned int* xu = (const unsigned int*)x_bf;
    const unsigned int* ru = (const unsigned int*)rel_bf;
    float ax = 0.f, ay = 0.f;
    int j = 0;
    for (; j + 2 <= cc; j += 2) {
        int4 two = *(const int4*)(sl + j);
        unsigned int xa = xu[(size_t)two.x * 64 + lane];
        unsigned int ra = ru[(size_t)two.y * 64 + lane];
        unsigned int xb = xu[(size_t)two.z * 64 + lane];
        unsigned int rb = ru[(size_t)two.w * 64 + lane];
        ax += bf2f(xa & 0xffffu) + bf2f(ra & 0xffffu)
            + bf2f(xb & 0xffffu) + bf2f(rb & 0xffffu);
        ay += bf2f(xa >> 16) + bf2f(ra >> 16)
            + bf2f(xb >> 16) + bf2f(rb >> 16);
    }
    if (j < cc) {
        int2 se = sl[j];
        unsigned int xa = xu[(size_t)se.x * 64 + lane];
        unsigned int ra = ru[(size_t)se.y * 64 + lane];
        ax += bf2f(xa & 0xffffu) + bf2f(ra & 0xffffu);
        ay += bf2f(xa >> 16) + bf2f(ra >> 16);
    }
    float inv = 1.f / fmaxf((float)c, 1.f);
    unsigned int pack = (unsigned int)f2bf(ax * inv)
                      | ((unsigned int)f2bf(ay * inv) << 16);
    ((unsigned int*)tokens)[((size_t)n * 5 + w + 1) * 64 + lane] = pack;
    if (w == 0)
        ((unsigned int*)tokens)[((size_t)n * 5) * 64 + lane] = xu[(size_t)n * 64 + lane];
}

// ---------------------------------------------------------------------------
// GEMM1: Z[M,288] = tokens @ Wcat -> delta (softplus), bc, g.
// ---------------------------------------------------------------------------
__global__ __launch_bounds__(256) void mfma_gemm(
    const unsigned short* __restrict__ tokens,
    const unsigned short* __restrict__ Bp,
    const float* __restrict__ b_delta, const float* __restrict__ b_g,
    unsigned short* __restrict__ delta,
    unsigned short* __restrict__ bc,
    unsigned short* __restrict__ g)
{
    int m0 = blockIdx.x * 64, n0 = blockIdx.y * 64;
    int wv = threadIdx.x >> 6, lane = threadIdx.x & 63;
    int quad = lane >> 4, l16 = lane & 15;

    f32x4 acc[4] = {{0,0,0,0},{0,0,0,0},{0,0,0,0},{0,0,0,0}};
    const unsigned short* arow = tokens + (size_t)(m0 + wv * 16 + l16) * 128 + quad * 8;
    #pragma unroll
    for (int kc = 0; kc < 128; kc += 32) {
        bf16x8 a = *(const bf16x8*)(arow + kc);
        #pragma unroll
        for (int t = 0; t < 4; ++t) {
            bf16x8 b = *(const bf16x8*)(Bp + ((size_t)(kc / 8 + quad) * NPAD + n0 + 16 * t + l16) * 8);
            acc[t] = __builtin_amdgcn_mfma_f32_16x16x32_bf16(a, b, acc[t], 0, 0, 0);
        }
    }

    int rbase = m0 + wv * 16 + quad * 4;
    #pragma unroll
    for (int t = 0; t < 4; ++t) {
        int c = n0 + 16 * t + l16;
        #pragma unroll
        for (int reg = 0; reg < 4; ++reg) {
            int r = rbase + reg;
            if (r >= M_ROWS) continue;
            float v = acc[t][reg];
            if (c < 128) {
                float z = v + b_delta[c];
                float d = (z > 15.f) ? z : log1pf(__expf(z));
                delta[(size_t)r * 128 + c] = f2bf(d);
            } else if (c < 160) {
                bc[(size_t)r * 32 + (c - 128)] = f2bf(v);
            } else if (c < 288) {
                int rq = r / 5;
                if (r - rq * 5 == 0)
                    g[(size_t)rq * 128 + (c - 160)] = f2bf(v + b_g[c - 160]);
            }
        }
    }
}

// ---------------------------------------------------------------------------
// Scan: so = mean_s(y_fwd + y_bwd); exp(delta*A) computed once, reused.
// ---------------------------------------------------------------------------
__global__ __launch_bounds__(128) void scan_so(
    const unsigned short* __restrict__ tokens,
    const unsigned short* __restrict__ delta,
    const unsigned short* __restrict__ bcbuf,
    const float* __restrict__ log_A,
    unsigned short* __restrict__ so)
{
    int n = blockIdx.x, tid = threadIdx.x;
    __shared__ __align__(16) float BC[160];

    for (int idx = tid; idx < 160; idx += 128) {
        int s = idx >> 5, q = idx & 31;
        BC[idx] = bf2f(bcbuf[((size_t)n * 5 + s) * 32 + q]);
    }
    float tv[5], dl[5];
    #pragma unroll
    for (int s = 0; s < 5; ++s) {
        tv[s] = bf2f(tokens[((size_t)n * 5 + s) * 128 + tid]);
        dl[s] = bf2f(delta[((size_t)n * 5 + s) * 128 + tid]);
    }
    float Ac[16];
    {
        const float4* la = (const float4*)(log_A + tid * 16);
        #pragma unroll
        for (int q = 0; q < 4; ++q) {
            float4 lv = la[q];
            Ac[q * 4 + 0] = -__expf(lv.x);
            Ac[q * 4 + 1] = -__expf(lv.y);
            Ac[q * 4 + 2] = -__expf(lv.z);
            Ac[q * 4 + 3] = -__expf(lv.w);
        }
    }
    __syncthreads();

    float Af[5][16];
    float total = 0.f;
    {   // forward — computes and stores Af
        float st[16];
        #pragma unroll
        for (int k = 0; k < 16; ++k) st[k] = 0.f;
        #pragma unroll
        for (int s = 0; s < 5; ++s) {
            float dtv = dl[s] * tv[s];
            float y = 0.f;
            #pragma unroll
            for (int k = 0; k < 16; ++k) {
                float A = __expf(dl[s] * Ac[k]);
                Af[s][k] = A;
                st[k] = fmaf(A, st[k], dtv * BC[s * 32 + k]);
                y = fmaf(st[k], BC[s * 32 + 16 + k], y);
            }
            total += y;
        }
    }
    {   // backward — reuses Af
        float st[16];
        #pragma unroll
        for (int k = 0; k < 16; ++k) st[k] = 0.f;
        #pragma unroll
        for (int s = 4; s >= 0; --s) {
            float dtv = dl[s] * tv[s];
            float y = 0.f;
            #pragma unroll
            for (int k = 0; k < 16; ++k) {
                st[k] = fmaf(Af[s][k], st[k], dtv * BC[s * 32 + k]);
                y = fmaf(st[k], BC[s * 32 + 16 + k], y);
            }
            total += y;
        }
    }
    so[(size_t)n * 128 + tid] = f2bf(total * 0.2f);
}

// ---------------------------------------------------------------------------
// GEMM2: out = LN(x + silu(g)*(so @ W_out + b_out)). 16-row tiles, 625 blocks.
// ---------------------------------------------------------------------------
__global__ __launch_bounds__(256) void out_gemm(
    const unsigned short* __restrict__ so,
    const unsigned short* __restrict__ Wop,
    const unsigned short* __restrict__ gbuf,
    const float* __restrict__ x,
    const float* __restrict__ b_out,
    const float* __restrict__ ln_g, const float* __restrict__ ln_b,
    float* __restrict__ out)
{
    int m0 = blockIdx.x * 16;
    int tid = threadIdx.x;
    int wv = tid >> 6, lane = tid & 63;
    int quad = lane >> 4, l16 = lane & 15;

    __shared__ float res[16 * 132];
    __shared__ float pmu[16][16];
    __shared__ float pv2[16][16];
    __shared__ float muA[16], rstdA[16];

    f32x4 acc[2] = {{0,0,0,0},{0,0,0,0}};
    const unsigned short* arow = so + (size_t)(m0 + l16) * 128 + quad * 8;
    #pragma unroll
    for (int kc = 0; kc < 128; kc += 32) {
        bf16x8 a = *(const bf16x8*)(arow + kc);
        #pragma unroll
        for (int tt = 0; tt < 2; ++tt) {
            int t = wv * 2 + tt;
            bf16x8 b = *(const bf16x8*)(Wop + ((size_t)(kc / 8 + quad) * 128 + 16 * t + l16) * 8);
            acc[tt] = __builtin_amdgcn_mfma_f32_16x16x32_bf16(a, b, acc[tt], 0, 0, 0);
        }
    }

    #pragma unroll
    for (int tt = 0; tt < 2; ++tt) {
        int c = wv * 32 + tt * 16 + l16;
        #pragma unroll
        for (int reg = 0; reg < 4; ++reg) {
            int lrow = quad * 4 + reg;
            int r = m0 + lrow;
            float o = acc[tt][reg] + b_out[c];
            float gl = bf2f(gbuf[(size_t)r * 128 + c]);
            float gate = gl / (1.f + __expf(-gl));
            res[lrow * 132 + c] = x[(size_t)r * 128 + c] + gate * o;
        }
    }
    __syncthreads();

    {
        int row = tid >> 4, q = tid & 15;
        float s = 0.f, s2 = 0.f;
        #pragma unroll
        for (int i = 0; i < 8; ++i) {
            float v = res[row * 132 + q + 16 * i];
            s += v; s2 += v * v;
        }
        pmu[row][q] = s; pv2[row][q] = s2;
    }
    __syncthreads();
    if (tid < 16) {
        float s = 0.f, s2 = 0.f;
        #pragma unroll
        for (int i = 0; i < 16; ++i) { s += pmu[tid][i]; s2 += pv2[tid][i]; }
        float mu = s * (1.f / 128.f);
        float var = s2 * (1.f / 128.f) - mu * mu;
        muA[tid] = mu;
        rstdA[tid] = rsqrtf(var + LN_EPS);
    }
    __syncthreads();
    #pragma unroll
    for (int i = 0; i < 8; ++i) {
        int idx = i * 256 + tid;
        int row = idx >> 7, c = idx & 127;
        out[(size_t)(m0 + row) * 128 + c] =
            (res[row * 132 + c] - muA[row]) * rstdA[row] * ln_g[c] + ln_b[c];
    }
}

// ---------------------------------------------------------------------------
extern "C" void kernel_launch(void* const* d_in, const int* in_sizes, int n_in,
                              void* d_out, int out_size, void* d_ws, size_t ws_size,
                              hipStream_t stream) {
    const float* x          = (const float*)d_in[0];
    const int*   edge_index = (const int*)  d_in[1];
    const int*   edge_type  = (const int*)  d_in[2];
    const int*   perms      = (const int*)  d_in[3];
    const float* rel_table  = (const float*)d_in[4];
    const float* log_A      = (const float*)d_in[5];
    const float* W_B        = (const float*)d_in[6];
    const float* W_C        = (const float*)d_in[7];
    const float* W_delta    = (const float*)d_in[8];
    const float* b_delta    = (const float*)d_in[9];
    const float* W_g        = (const float*)d_in[10];
    const float* b_g        = (const float*)d_in[11];
    const float* W_out      = (const float*)d_in[12];
    const float* b_out      = (const float*)d_in[13];
    const float* ln_g       = (const float*)d_in[14];
    const float* ln_b       = (const float*)d_in[15];

    char* ws = (char*)d_ws;
    int*            cnt    = (int*)           (ws + 0);          //   163840
    unsigned short* Bp     = (unsigned short*)(ws + 163840);     //    81920
    unsigned short* Wop    = (unsigned short*)(ws + 245760);     //    32768
    unsigned short* x_bf   = (unsigned short*)(ws + 278528);     //  2560000
    unsigned short* rel_bf = (unsigned short*)(ws + 2838528);    //    51200
    unsigned short* tokens = (unsigned short*)(ws + 2889728);    // 12812288
    unsigned short* g      = (unsigned short*)(ws + 15702016);   //  2560000
    unsigned short* so     = (unsigned short*)(ws + 18262016);   //  2560000
    unsigned short* bc     = (unsigned short*)(ws + 20822016);   //  3200000
    // union: slots (consumed by gather) aliased with delta (written by gemm1)
    int2*           slots  = (int2*)          (ws + 24022016);   // 10485760
    unsigned short* delta  = (unsigned short*)(ws + 24022016);   // 12812288

    prep_all<<<(123904 + N_NODES * D_MODEL + 255) / 256, 256, 0, stream>>>(
        W_delta, W_B, W_C, W_g, W_out, x, rel_table,
        Bp, Wop, x_bf, rel_bf, cnt);

    csr_build<<<(4 * P_EDGES + 255) / 256, 256, 0, stream>>>(
        edge_index, edge_type, perms, cnt, slots);

    gather_tokens<<<N_NODES, 256, 0, stream>>>(
        x_bf, cnt, slots, rel_bf, tokens);

    mfma_gemm<<<dim3(M_PAD / 64, NPAD / 64), 256, 0, stream>>>(
        tokens, Bp, b_delta, b_g, delta, bc, g);

    scan_so<<<N_NODES, 128, 0, stream>>>(
        tokens, delta, bc, log_A, so);

    out_gemm<<<N_NODES / 16, 256, 0, stream>>>(
        so, Wop, g, x, b_out, ln_g, ln_b, (float*)d_out);
}

// Round 6
// 202.447 us; speedup vs baseline: 4.0579x; 1.0123x over previous
//
#include <hip/hip_runtime.h>
#include <hip/hip_bf16.h>
#include <math.h>

#define N_NODES 10000
#define D_MODEL 128
#define E_EDGES 320000
#define P_EDGES 80000
#define LN_EPS 1e-5f
#define NBUCK 40960        // 4*N padded
#define CAP 32             // slots per bucket (Poisson(8): P(>32) ~ 1e-11)
#define M_ROWS 50000
#define M_PAD  50048       // 782*64
#define NPAD   320         // 288 cols padded

typedef __attribute__((ext_vector_type(8))) short bf16x8;
typedef __attribute__((ext_vector_type(4))) float f32x4;

__device__ __forceinline__ unsigned short f2bf(float f) {
    __hip_bfloat16 h = __float2bfloat16(f);
    return *reinterpret_cast<unsigned short*>(&h);
}
__device__ __forceinline__ float bf2f(unsigned int u) {
    return __uint_as_float(u << 16);
}

// ---------------------------------------------------------------------------
// prep_all: pack Wcat + W_out (B-frag layout), x/rel -> bf16, zero counters,
// pack edge triples into ed4 (one 16B random load later instead of three 4B).
// gid ranges: [0,40960) Bp | [40960,57344) Wop | [57344,98304) cnt |
// [98304,123904) rel_bf | [123904,1403904) x_bf | [1403904,1723904) ed4
// ---------------------------------------------------------------------------
__global__ __launch_bounds__(256) void prep_all(
    const float* __restrict__ Wd, const float* __restrict__ Wb,
    const float* __restrict__ Wc, const float* __restrict__ Wg,
    const float* __restrict__ W_out,
    const float* __restrict__ x, const float* __restrict__ rel,
    const int* __restrict__ edge_index, const int* __restrict__ edge_type,
    unsigned short* __restrict__ Bp, unsigned short* __restrict__ Wop,
    unsigned short* __restrict__ x_bf, unsigned short* __restrict__ rel_bf,
    int* __restrict__ cnt, int4* __restrict__ ed4)
{
    int gid = blockIdx.x * 256 + threadIdx.x;
    if (gid < 40960) {
        int k = gid / NPAD, n = gid - (gid / NPAD) * NPAD;
        float v = 0.f;
        if (n < 128)      v = Wd[k * 128 + n];
        else if (n < 144) v = Wb[k * 16 + (n - 128)];
        else if (n < 160) v = Wc[k * 16 + (n - 144)];
        else if (n < 288) v = Wg[k * 128 + (n - 160)];
        Bp[((size_t)(k >> 3) * NPAD + n) * 8 + (k & 7)] = f2bf(v);
    } else if (gid < 57344) {
        int i = gid - 40960;
        int k = i >> 7, n = i & 127;
        Wop[((size_t)(k >> 3) * 128 + n) * 8 + (k & 7)] = f2bf(W_out[k * 128 + n]);
    } else if (gid < 98304) {
        cnt[gid - 57344] = 0;
    } else if (gid < 123904) {
        int i = gid - 98304;
        rel_bf[i] = f2bf(rel[i]);
    } else if (gid < 1403904) {
        int i = gid - 123904;
        x_bf[i] = f2bf(x[i]);
    } else if (gid < 1723904) {
        int e = gid - 1403904;
        ed4[e] = make_int4(edge_index[e], edge_index[E_EDGES + e], edge_type[e], 0);
    }
}

// ---------------------------------------------------------------------------
// One-pass CSR into fixed-capacity bucket slots (1 random 16B load per edge).
// ---------------------------------------------------------------------------
__global__ __launch_bounds__(256) void csr_build(
    const int4* __restrict__ ed4, const int* __restrict__ perms,
    int* __restrict__ cnt, int2* __restrict__ slots)
{
    int gid = blockIdx.x * blockDim.x + threadIdx.x;
    if (gid >= 4 * P_EDGES) return;
    int s = gid / P_EDGES;
    int e = perms[gid];
    int4 ed = ed4[e];                       // (src, dst, et, 0)
    int b = ed.y * 4 + s;
    int pos = atomicAdd(&cnt[b], 1);
    if (pos < CAP) slots[(size_t)b * CAP + pos] = make_int2(ed.x, ed.z);
}

// ---------------------------------------------------------------------------
// Gather (bf16): one wave per bucket; lane = 2 dims; 4 edges in flight.
// ---------------------------------------------------------------------------
__global__ __launch_bounds__(256) void gather_tokens(
    const unsigned short* __restrict__ x_bf,
    const int* __restrict__ cnt, const int2* __restrict__ slots,
    const unsigned short* __restrict__ rel_bf,
    unsigned short* __restrict__ tokens)
{
    int n = blockIdx.x;
    int w = threadIdx.x >> 6, lane = threadIdx.x & 63;
    int b = n * 4 + w;
    int c = cnt[b];
    int cc = c < CAP ? c : CAP;
    const int2* sl = slots + (size_t)b * CAP;
    const unsigned int* xu = (const unsigned int*)x_bf;
    const unsigned int* ru = (const unsigned int*)rel_bf;
    float ax = 0.f, ay = 0.f;
    int j = 0;
    for (; j + 4 <= cc; j += 4) {
        int4 e01 = *(const int4*)(sl + j);
        int4 e23 = *(const int4*)(sl + j + 2);
        unsigned int x0 = xu[(size_t)e01.x * 64 + lane];
        unsigned int r0 = ru[(size_t)e01.y * 64 + lane];
        unsigned int x1 = xu[(size_t)e01.z * 64 + lane];
        unsigned int r1 = ru[(size_t)e01.w * 64 + lane];
        unsigned int x2 = xu[(size_t)e23.x * 64 + lane];
        unsigned int r2 = ru[(size_t)e23.y * 64 + lane];
        unsigned int x3 = xu[(size_t)e23.z * 64 + lane];
        unsigned int r3 = ru[(size_t)e23.w * 64 + lane];
        ax += (bf2f(x0 & 0xffffu) + bf2f(r0 & 0xffffu))
            + (bf2f(x1 & 0xffffu) + bf2f(r1 & 0xffffu))
            + (bf2f(x2 & 0xffffu) + bf2f(r2 & 0xffffu))
            + (bf2f(x3 & 0xffffu) + bf2f(r3 & 0xffffu));
        ay += (bf2f(x0 >> 16) + bf2f(r0 >> 16))
            + (bf2f(x1 >> 16) + bf2f(r1 >> 16))
            + (bf2f(x2 >> 16) + bf2f(r2 >> 16))
            + (bf2f(x3 >> 16) + bf2f(r3 >> 16));
    }
    if (j + 2 <= cc) {
        int4 e01 = *(const int4*)(sl + j);
        unsigned int x0 = xu[(size_t)e01.x * 64 + lane];
        unsigned int r0 = ru[(size_t)e01.y * 64 + lane];
        unsigned int x1 = xu[(size_t)e01.z * 64 + lane];
        unsigned int r1 = ru[(size_t)e01.w * 64 + lane];
        ax += (bf2f(x0 & 0xffffu) + bf2f(r0 & 0xffffu))
            + (bf2f(x1 & 0xffffu) + bf2f(r1 & 0xffffu));
        ay += (bf2f(x0 >> 16) + bf2f(r0 >> 16))
            + (bf2f(x1 >> 16) + bf2f(r1 >> 16));
        j += 2;
    }
    if (j < cc) {
        int2 se = sl[j];
        unsigned int xa = xu[(size_t)se.x * 64 + lane];
        unsigned int ra = ru[(size_t)se.y * 64 + lane];
        ax += bf2f(xa & 0xffffu) + bf2f(ra & 0xffffu);
        ay += bf2f(xa >> 16) + bf2f(ra >> 16);
    }
    float inv = 1.f / fmaxf((float)c, 1.f);
    unsigned int pack = (unsigned int)f2bf(ax * inv)
                      | ((unsigned int)f2bf(ay * inv) << 16);
    ((unsigned int*)tokens)[((size_t)n * 5 + w + 1) * 64 + lane] = pack;
    if (w == 0)
        ((unsigned int*)tokens)[((size_t)n * 5) * 64 + lane] = xu[(size_t)n * 64 + lane];
}

// ---------------------------------------------------------------------------
// GEMM1: Z[M,288] = tokens @ Wcat -> delta (softplus), bc, g.
// ---------------------------------------------------------------------------
__global__ __launch_bounds__(256) void mfma_gemm(
    const unsigned short* __restrict__ tokens,
    const unsigned short* __restrict__ Bp,
    const float* __restrict__ b_delta, const float* __restrict__ b_g,
    unsigned short* __restrict__ delta,
    unsigned short* __restrict__ bc,
    unsigned short* __restrict__ g)
{
    int m0 = blockIdx.x * 64, n0 = blockIdx.y * 64;
    int wv = threadIdx.x >> 6, lane = threadIdx.x & 63;
    int quad = lane >> 4, l16 = lane & 15;

    f32x4 acc[4] = {{0,0,0,0},{0,0,0,0},{0,0,0,0},{0,0,0,0}};
    const unsigned short* arow = tokens + (size_t)(m0 + wv * 16 + l16) * 128 + quad * 8;
    #pragma unroll
    for (int kc = 0; kc < 128; kc += 32) {
        bf16x8 a = *(const bf16x8*)(arow + kc);
        #pragma unroll
        for (int t = 0; t < 4; ++t) {
            bf16x8 b = *(const bf16x8*)(Bp + ((size_t)(kc / 8 + quad) * NPAD + n0 + 16 * t + l16) * 8);
            acc[t] = __builtin_amdgcn_mfma_f32_16x16x32_bf16(a, b, acc[t], 0, 0, 0);
        }
    }

    int rbase = m0 + wv * 16 + quad * 4;
    #pragma unroll
    for (int t = 0; t < 4; ++t) {
        int c = n0 + 16 * t + l16;
        #pragma unroll
        for (int reg = 0; reg < 4; ++reg) {
            int r = rbase + reg;
            if (r >= M_ROWS) continue;
            float v = acc[t][reg];
            if (c < 128) {
                float z = v + b_delta[c];
                float d = (z > 15.f) ? z : log1pf(__expf(z));
                delta[(size_t)r * 128 + c] = f2bf(d);
            } else if (c < 160) {
                bc[(size_t)r * 32 + (c - 128)] = f2bf(v);
            } else if (c < 288) {
                int rq = r / 5;
                if (r - rq * 5 == 0)
                    g[(size_t)rq * 128 + (c - 160)] = f2bf(v + b_g[c - 160]);
            }
        }
    }
}

// ---------------------------------------------------------------------------
// Fused scan + out-GEMM + gate + layernorm. Block = 16 nodes, 256 threads.
// Each thread scans 8 (node,dim) pairs (d fixed per thread -> Ac hoisted),
// so goes to LDS bf16 and feeds the MFMA A-fragment directly.
// ---------------------------------------------------------------------------
__global__ __launch_bounds__(256) void scan_out(
    const unsigned short* __restrict__ tokens,
    const unsigned short* __restrict__ delta,
    const unsigned short* __restrict__ bcbuf,
    const float* __restrict__ log_A,
    const unsigned short* __restrict__ Wop,
    const unsigned short* __restrict__ gbuf,
    const float* __restrict__ x,
    const float* __restrict__ b_out,
    const float* __restrict__ ln_g, const float* __restrict__ ln_b,
    float* __restrict__ out)
{
    int m0 = blockIdx.x * 16;
    int t = threadIdx.x;

    __shared__ float BCs[16][160];
    __shared__ unsigned short soL[16][128];
    __shared__ float res[16 * 132];
    __shared__ float pmu[16][16];
    __shared__ float pv2[16][16];
    __shared__ float muA[16], rstdA[16];

    for (int idx = t; idx < 2560; idx += 256) {
        int n = idx / 160, rem = idx - n * 160;
        int s = rem >> 5, q = rem & 31;
        BCs[n][rem] = bf2f(bcbuf[((size_t)(m0 + n) * 5 + s) * 32 + q]);
    }

    const int d = t & 127;
    float Ac[16];
    {
        const float4* la = (const float4*)(log_A + d * 16);
        #pragma unroll
        for (int q = 0; q < 4; ++q) {
            float4 lv = la[q];
            Ac[q * 4 + 0] = -__expf(lv.x);
            Ac[q * 4 + 1] = -__expf(lv.y);
            Ac[q * 4 + 2] = -__expf(lv.z);
            Ac[q * 4 + 3] = -__expf(lv.w);
        }
    }
    __syncthreads();

    #pragma unroll 1
    for (int i = 0; i < 8; ++i) {
        int n = 2 * i + (t >> 7);
        const unsigned short* tb = tokens + ((size_t)(m0 + n) * 5) * 128 + d;
        const unsigned short* db = delta  + ((size_t)(m0 + n) * 5) * 128 + d;
        float tv[5], dl[5];
        #pragma unroll
        for (int s = 0; s < 5; ++s) {
            tv[s] = bf2f(tb[s * 128]);
            dl[s] = bf2f(db[s * 128]);
        }
        const float* BCn = BCs[n];

        float Af[5][16];
        float total = 0.f;
        {   // forward — computes and stores Af
            float st[16];
            #pragma unroll
            for (int k = 0; k < 16; ++k) st[k] = 0.f;
            #pragma unroll
            for (int s = 0; s < 5; ++s) {
                float dtv = dl[s] * tv[s];
                float y = 0.f;
                #pragma unroll
                for (int k = 0; k < 16; ++k) {
                    float A = __expf(dl[s] * Ac[k]);
                    Af[s][k] = A;
                    st[k] = fmaf(A, st[k], dtv * BCn[s * 32 + k]);
                    y = fmaf(st[k], BCn[s * 32 + 16 + k], y);
                }
                total += y;
            }
        }
        {   // backward — reuses Af
            float st[16];
            #pragma unroll
            for (int k = 0; k < 16; ++k) st[k] = 0.f;
            #pragma unroll
            for (int s = 4; s >= 0; --s) {
                float dtv = dl[s] * tv[s];
                float y = 0.f;
                #pragma unroll
                for (int k = 0; k < 16; ++k) {
                    st[k] = fmaf(Af[s][k], st[k], dtv * BCn[s * 32 + k]);
                    y = fmaf(st[k], BCn[s * 32 + 16 + k], y);
                }
                total += y;
            }
        }
        soL[n][d] = f2bf(total * 0.2f);
    }
    __syncthreads();

    // ---- MFMA: res16x128 = soL @ W_out ----
    int wv = t >> 6, lane = t & 63;
    int quad = lane >> 4, l16 = lane & 15;
    f32x4 acc[2] = {{0,0,0,0},{0,0,0,0}};
    #pragma unroll
    for (int kc = 0; kc < 128; kc += 32) {
        bf16x8 a = *(const bf16x8*)&soL[l16][kc + quad * 8];
        #pragma unroll
        for (int tt = 0; tt < 2; ++tt) {
            int tc = wv * 2 + tt;
            bf16x8 b = *(const bf16x8*)(Wop + ((size_t)(kc / 8 + quad) * 128 + 16 * tc + l16) * 8);
            acc[tt] = __builtin_amdgcn_mfma_f32_16x16x32_bf16(a, b, acc[tt], 0, 0, 0);
        }
    }

    #pragma unroll
    for (int tt = 0; tt < 2; ++tt) {
        int c = wv * 32 + tt * 16 + l16;
        #pragma unroll
        for (int reg = 0; reg < 4; ++reg) {
            int lrow = quad * 4 + reg;
            int r = m0 + lrow;
            float o = acc[tt][reg] + b_out[c];
            float gl = bf2f(gbuf[(size_t)r * 128 + c]);
            float gate = gl / (1.f + __expf(-gl));
            res[lrow * 132 + c] = x[(size_t)r * 128 + c] + gate * o;
        }
    }
    __syncthreads();

    {
        int row = t >> 4, q = t & 15;
        float s = 0.f, s2 = 0.f;
        #pragma unroll
        for (int i = 0; i < 8; ++i) {
            float v = res[row * 132 + q + 16 * i];
            s += v; s2 += v * v;
        }
        pmu[row][q] = s; pv2[row][q] = s2;
    }
    __syncthreads();
    if (t < 16) {
        float s = 0.f, s2 = 0.f;
        #pragma unroll
        for (int i = 0; i < 16; ++i) { s += pmu[t][i]; s2 += pv2[t][i]; }
        float mu = s * (1.f / 128.f);
        float var = s2 * (1.f / 128.f) - mu * mu;
        muA[t] = mu;
        rstdA[t] = rsqrtf(var + LN_EPS);
    }
    __syncthreads();
    #pragma unroll
    for (int i = 0; i < 8; ++i) {
        int idx = i * 256 + t;
        int row = idx >> 7, c = idx & 127;
        out[(size_t)(m0 + row) * 128 + c] =
            (res[row * 132 + c] - muA[row]) * rstdA[row] * ln_g[c] + ln_b[c];
    }
}

// ---------------------------------------------------------------------------
extern "C" void kernel_launch(void* const* d_in, const int* in_sizes, int n_in,
                              void* d_out, int out_size, void* d_ws, size_t ws_size,
                              hipStream_t stream) {
    const float* x          = (const float*)d_in[0];
    const int*   edge_index = (const int*)  d_in[1];
    const int*   edge_type  = (const int*)  d_in[2];
    const int*   perms      = (const int*)  d_in[3];
    const float* rel_table  = (const float*)d_in[4];
    const float* log_A      = (const float*)d_in[5];
    const float* W_B        = (const float*)d_in[6];
    const float* W_C        = (const float*)d_in[7];
    const float* W_delta    = (const float*)d_in[8];
    const float* b_delta    = (const float*)d_in[9];
    const float* W_g        = (const float*)d_in[10];
    const float* b_g        = (const float*)d_in[11];
    const float* W_out      = (const float*)d_in[12];
    const float* b_out      = (const float*)d_in[13];
    const float* ln_g       = (const float*)d_in[14];
    const float* ln_b       = (const float*)d_in[15];

    char* ws = (char*)d_ws;
    int*            cnt    = (int*)           (ws + 0);          //   163840
    unsigned short* Bp     = (unsigned short*)(ws + 163840);     //    81920
    unsigned short* Wop    = (unsigned short*)(ws + 245760);     //    32768
    unsigned short* x_bf   = (unsigned short*)(ws + 278528);     //  2560000
    unsigned short* rel_bf = (unsigned short*)(ws + 2838528);    //    51200
    int4*           ed4    = (int4*)          (ws + 2889728);    //  5120000
    unsigned short* tokens = (unsigned short*)(ws + 8009728);    // 12812288
    unsigned short* g      = (unsigned short*)(ws + 20822016);   //  2560000
    unsigned short* bc     = (unsigned short*)(ws + 23382016);   //  3200000
    // union: slots (consumed by gather) aliased with delta (written by gemm1)
    int2*           slots  = (int2*)          (ws + 26582016);   // 10485760
    unsigned short* delta  = (unsigned short*)(ws + 26582016);   // 12812288

    prep_all<<<(1723904 + 255) / 256, 256, 0, stream>>>(
        W_delta, W_B, W_C, W_g, W_out, x, rel_table, edge_index, edge_type,
        Bp, Wop, x_bf, rel_bf, cnt, ed4);

    csr_build<<<(4 * P_EDGES + 255) / 256, 256, 0, stream>>>(
        ed4, perms, cnt, slots);

    gather_tokens<<<N_NODES, 256, 0, stream>>>(
        x_bf, cnt, slots, rel_bf, tokens);

    mfma_gemm<<<dim3(M_PAD / 64, NPAD / 64), 256, 0, stream>>>(
        tokens, Bp, b_delta, b_g, delta, bc, g);

    scan_out<<<N_NODES / 16, 256, 0, stream>>>(
        tokens, delta, bc, log_A, Wop, g, x, b_out, ln_g, ln_b, (float*)d_out);
}